// Round 12
// baseline (1476.224 us; speedup 1.0000x reference)
//
#include <hip/hip_runtime.h>
#include <math.h>

// ---------- types ----------
typedef __bf16 bf16_t;
typedef __bf16 bf16x8 __attribute__((ext_vector_type(8)));
typedef __bf16 bf16x4 __attribute__((ext_vector_type(4)));
typedef float  f32x4  __attribute__((ext_vector_type(4)));

#define NN 8192      // mesh nodes
#define RA 8320      // A rows: 8192 adj + 64 INV + 64 zero pad
#define GPS256 2129920u  // RA*256 floats: stride between split partials (N=256, 8 splits)
#define GPS512 4259840u  // RA*512 floats: stride between split partials (N=512, 4 splits)
#define XPAD 68
#define X2PAD 132
#define ZTPAD 66

__device__ __forceinline__ float gelu_f(float x) {
    return 0.5f * x * (1.0f + erff(x * 0.70710678118654752f));
}

__device__ __forceinline__ float wsum64(float v) {
#pragma unroll
    for (int m = 32; m; m >>= 1) v += __shfl_xor(v, m);
    return v;
}

// sum 8 split partials (N=256 GEMMs)
__device__ __forceinline__ float gp8(const float* __restrict__ Gp, size_t gi) {
    float a = Gp[gi] + Gp[gi + (size_t)GPS256];
    float b = Gp[gi + 2 * (size_t)GPS256] + Gp[gi + 3 * (size_t)GPS256];
    float c = Gp[gi + 4 * (size_t)GPS256] + Gp[gi + 5 * (size_t)GPS256];
    float d = Gp[gi + 6 * (size_t)GPS256] + Gp[gi + 7 * (size_t)GPS256];
    return (a + b) + (c + d);
}

// sum ns split partials, runtime ns (4 or 8)
__device__ __forceinline__ float gpn(const float* __restrict__ Gp, size_t gi, size_t st, int ns) {
    float v = Gp[gi];
    for (int s = 1; s < ns; ++s) v += Gp[gi + (size_t)s * st];
    return v;
}

__device__ __forceinline__ void async16(const void* g, void* l) {
    __builtin_amdgcn_global_load_lds(
        (const __attribute__((address_space(1))) unsigned int*)g,
        (__attribute__((address_space(3))) unsigned int*)l,
        16, 0, 0);
}

// 16-rows-per-thread tile matmul: acc[i] += sum_k X[r0+i][k] * W[k*ws + c]
__device__ __forceinline__ void mm16(const float* __restrict__ X, int xpad,
                                     const float* __restrict__ W, int ws, int K,
                                     int c, int r0, float* acc) {
    for (int k0 = 0; k0 < K; k0 += 4) {
        float w0 = W[(size_t)(k0 + 0) * ws + c];
        float w1 = W[(size_t)(k0 + 1) * ws + c];
        float w2 = W[(size_t)(k0 + 2) * ws + c];
        float w3 = W[(size_t)(k0 + 3) * ws + c];
#pragma unroll
        for (int i = 0; i < 16; ++i) {
            float4 xv = *(const float4*)(X + (size_t)(r0 + i) * xpad + k0);
            acc[i] = fmaf(xv.x, w0, acc[i]);
            acc[i] = fmaf(xv.y, w1, acc[i]);
            acc[i] = fmaf(xv.z, w2, acc[i]);
            acc[i] = fmaf(xv.w, w3, acc[i]);
        }
    }
}

// ---------- adj+INV fp32 -> bf16 + adj row sums (grid 8320) ----------
__global__ __launch_bounds__(256) void k_adj_convert(const float* __restrict__ adj,
                                                     const float* __restrict__ INV,
                                                     bf16_t* __restrict__ adjB,
                                                     float* __restrict__ rowsum) {
    int row = blockIdx.x;
    int t = threadIdx.x;
    bf16_t* br = adjB + (size_t)row * NN;
    if (row >= NN + 64) {
        bf16x4 zz; zz[0] = zz[1] = zz[2] = zz[3] = (bf16_t)0.f;
#pragma unroll
        for (int v = 0; v < 8; ++v) *(bf16x4*)(br + (v * 256 + t) * 4) = zz;
        return;
    }
    const float* ar = (row < NN) ? adj + (size_t)row * NN : INV + (size_t)(row - NN) * NN;
    float s = 0.f;
#pragma unroll
    for (int v = 0; v < 8; ++v) {
        int i = (v * 256 + t) * 4;
        float4 f = *(const float4*)(ar + i);
        s += f.x + f.y + f.z + f.w;
        bf16x4 o;
        o[0] = (bf16_t)f.x; o[1] = (bf16_t)f.y; o[2] = (bf16_t)f.z; o[3] = (bf16_t)f.w;
        *(bf16x4*)(br + i) = o;
    }
    if (row < NN) {
        s = wsum64(s);
        __shared__ float w4[4];
        if ((t & 63) == 0) w4[t >> 6] = s;
        __syncthreads();
        if (t == 0) rowsum[row] = w4[0] + w4[1] + w4[2] + w4[3];
    }
}

// ---------- fold fc0@fc01 -> W0b[5][64] ----------
__global__ __launch_bounds__(64) void k_fold(const float* __restrict__ fc0w, const float* __restrict__ fc0b,
                                             const float* __restrict__ fc01w, const float* __restrict__ fc01b,
                                             float* __restrict__ W0b) {
    int c = threadIdx.x;
#pragma unroll
    for (int j = 0; j < 4; ++j) {
        float a = 0.f;
        for (int k = 0; k < 64; ++k) a += fc0w[j * 64 + k] * fc01w[k * 64 + c];
        W0b[j * 64 + c] = a;
    }
    float b = fc01b[c];
    for (int k = 0; k < 64; ++k) b += fc0b[k] * fc01w[k * 64 + c];
    W0b[256 + c] = b;
}

// ---------- initial h (folded) + z0 -> Vt rows 256+ ----------
__global__ __launch_bounds__(256) void k_init_h(const float* __restrict__ x, const float* __restrict__ mesh,
                         const float* __restrict__ W0b,
                         const float* __restrict__ zg, const float* __restrict__ zb,
                         float* __restrict__ h, bf16_t* __restrict__ Vt) {
    __shared__ __align__(16) char buf[64 * ZTPAD * 2];
    bf16_t* ZT = (bf16_t*)buf;
    int t = threadIdx.x, c = t & 63, rq = t >> 6, r0 = rq * 16;
    int bb = blockIdx.x >> 7, n0 = (blockIdx.x & 127) * 64;
    float w0c = W0b[c], w1c = W0b[64 + c], w2c = W0b[128 + c], w3c = W0b[192 + c], b0c = W0b[256 + c];
    float gc = zg[c], bc = zb[c];
#pragma unroll
    for (int q = 0; q < 16; ++q) {
        int n = n0 + r0 + q;
        int w = bb * NN + n;
        float xv = x[w];
        float m0 = mesh[n * 3], m1 = mesh[n * 3 + 1], m2 = mesh[n * 3 + 2];
        float hv = b0c + xv * w0c + m0 * w1c + m1 * w2c + m2 * w3c;
        h[(size_t)w * 64 + c] = hv;
        float s = wsum64(hv), s2 = wsum64(hv * hv);
        float mean = s * (1.f / 64.f), var = s2 * (1.f / 64.f) - mean * mean;
        float z = (hv - mean) * rsqrtf(var + 1e-5f) * gc + bc;
        ZT[c * ZTPAD + r0 + q] = (bf16_t)z;
    }
    __syncthreads();
#pragma unroll
    for (int cc = 0; cc < 16; ++cc) {
        int c2 = r0 + cc;
        Vt[(size_t)(256 + bb * 64 + c2) * NN + n0 + c] = ZT[c2 * ZTPAD + c];
    }
}

// ---------- encoder pre -> Vt rows 0-255 ----------
__global__ __launch_bounds__(256) void k_enc_pre(const float* __restrict__ mesh,
                          const float* __restrict__ p1w, const float* __restrict__ p1b,
                          const float* __restrict__ p2w, const float* __restrict__ p2b,
                          const float* __restrict__ g1w, const float* __restrict__ g1b,
                          bf16_t* __restrict__ Vt) {
    __shared__ __align__(16) char buf[2 * 64 * XPAD * 4];
    float* X1 = (float*)buf;
    float* X2 = (float*)(buf + 64 * XPAD * 4);
    bf16_t* ZT = (bf16_t*)buf;
    int t = threadIdx.x, c = t & 63, rq = t >> 6, r0 = rq * 16;
    int ll = blockIdx.x >> 7, n0 = (blockIdx.x & 127) * 64;
    float p1b_c = p1b[ll * 64 + c];
    float p1w0 = p1w[(ll * 3 + 0) * 64 + c], p1w1 = p1w[(ll * 3 + 1) * 64 + c], p1w2 = p1w[(ll * 3 + 2) * 64 + c];
#pragma unroll
    for (int q = 0; q < 16; ++q) {
        int n = n0 + r0 + q;
        float m0 = mesh[n * 3], m1 = mesh[n * 3 + 1], m2 = mesh[n * 3 + 2];
        X1[(r0 + q) * XPAD + c] = gelu_f(p1b_c + m0 * p1w0 + m1 * p1w1 + m2 * p1w2);
    }
    __syncthreads();
    float e2[16];
#pragma unroll
    for (int i = 0; i < 16; ++i) e2[i] = p2b[ll * 64 + c];
    mm16(X1, XPAD, p2w + ll * 4096, 64, 64, c, r0, e2);
    __syncthreads();
#pragma unroll
    for (int q = 0; q < 16; ++q) X2[(r0 + q) * XPAD + c] = e2[q];
    __syncthreads();
    float tt[16];
#pragma unroll
    for (int i = 0; i < 16; ++i) tt[i] = g1b[ll * 64 + c];
    mm16(X2, XPAD, g1w + ll * 4096, 64, 64, c, r0, tt);
#pragma unroll
    for (int q = 0; q < 16; ++q) ZT[c * ZTPAD + r0 + q] = (bf16_t)tt[q];
    __syncthreads();
#pragma unroll
    for (int cc = 0; cc < 16; ++cc) {
        int c2 = r0 + cc;
        Vt[(size_t)(ll * 64 + c2) * NN + n0 + c] = ZT[c2 * ZTPAD + c];
    }
}

// ---------- encoder mid (reads Gp256, 8 splits) -> Vt rows 0-255 ----------
__global__ __launch_bounds__(256) void k_enc_mid(const float* __restrict__ Gp,
                          const float* __restrict__ g2w, const float* __restrict__ g2b,
                          bf16_t* __restrict__ Vt) {
    __shared__ __align__(16) char buf[64 * XPAD * 4 + 64 * ZTPAD * 2];
    float* X = (float*)buf;
    bf16_t* ZT = (bf16_t*)(buf + 64 * XPAD * 4);
    int t = threadIdx.x, c = t & 63, rq = t >> 6, r0 = rq * 16;
    int ll = blockIdx.x >> 7, n0 = (blockIdx.x & 127) * 64;
#pragma unroll
    for (int q = 0; q < 16; ++q) {
        int n = n0 + r0 + q;
        X[(r0 + q) * XPAD + c] = gelu_f(gp8(Gp, (size_t)n * 256 + ll * 64 + c));
    }
    __syncthreads();
    float t2[16];
#pragma unroll
    for (int i = 0; i < 16; ++i) t2[i] = g2b[ll * 64 + c];
    mm16(X, XPAD, g2w + ll * 4096, 64, 64, c, r0, t2);
#pragma unroll
    for (int q = 0; q < 16; ++q) ZT[c * ZTPAD + r0 + q] = (bf16_t)t2[q];
    __syncthreads();
#pragma unroll
    for (int cc = 0; cc < 16; ++cc) {
        int c2 = r0 + cc;
        Vt[(size_t)(ll * 64 + c2) * NN + n0 + c] = ZT[c2 * ZTPAD + c];
    }
}

// ---------- geo partials (reads merged Gp512, 4 splits, cols 0-255) ----------
__global__ void k_geo_part(const float* __restrict__ Gp,
                           const float* __restrict__ o1w, const float* __restrict__ o1b,
                           const float* __restrict__ o2w, const float* __restrict__ o2b,
                           const float* __restrict__ INV,
                           float* __restrict__ partials) {
    int l = blockIdx.x >> 7, chunk = blockIdx.x & 127;
    int n0 = chunk * 64;
    int t = threadIdx.x; // 0..63
    __shared__ float e4L[64][65];
    for (int r = 0; r < 64; ++r) {
        size_t gi = (size_t)(n0 + r) * 512 + l * 64 + t;
        e4L[r][t] = (Gp[gi] + Gp[gi + (size_t)GPS512])
                  + (Gp[gi + 2 * (size_t)GPS512] + Gp[gi + 3 * (size_t)GPS512]);
    }
    __syncthreads();
    float X[64];
#pragma unroll
    for (int i = 0; i < 64; ++i) X[i] = e4L[t][i];
    float e5[6] = {0, 0, 0, 0, 0, 0};
    const float* o1wl = o1w + (size_t)l * 64 * 128;
    const float* o2wl = o2w + (size_t)l * 128 * 6;
    for (int j = 0; j < 128; ++j) {
        float a = o1b[l * 128 + j];
#pragma unroll
        for (int i = 0; i < 64; ++i) a += X[i] * o1wl[i * 128 + j];
#pragma unroll
        for (int k = 0; k < 6; ++k) e5[k] += a * o2wl[j * 6 + k];
    }
#pragma unroll
    for (int k = 0; k < 6; ++k) e5[k] += o2b[l * 6 + k];
    __shared__ float e5L[64][8];
#pragma unroll
    for (int k = 0; k < 6; ++k) e5L[t][k] = e5[k];
    __syncthreads();
    float p[6] = {0, 0, 0, 0, 0, 0};
    const float* ivr = INV + (size_t)t * NN + n0;
    for (int r = 0; r < 64; ++r) {
        float iv = ivr[r];
#pragma unroll
        for (int k = 0; k < 6; ++k) p[k] += iv * e5L[r][k];
    }
#pragma unroll
    for (int k = 0; k < 6; ++k) partials[(size_t)(((l * 128 + chunk) * 64) + t) * 6 + k] = p[k];
}

// ---------- geo reduce + softmax ----------
__global__ void k_geo_final(const float* __restrict__ partials, float* __restrict__ geoT) {
    int l = blockIdx.x, m = threadIdx.x;
    float g[6] = {0, 0, 0, 0, 0, 0};
    for (int ch = 0; ch < 128; ++ch) {
#pragma unroll
        for (int k = 0; k < 6; ++k) g[k] += partials[(size_t)(((l * 128 + ch) * 64) + m) * 6 + k];
    }
    float mx = g[0];
#pragma unroll
    for (int k = 1; k < 6; ++k) mx = fmaxf(mx, g[k]);
    float s = 0.f;
#pragma unroll
    for (int k = 0; k < 6; ++k) { g[k] = expf(g[k] - mx); s += g[k]; }
    float inv = 1.f / s;
#pragma unroll
    for (int k = 0; k < 6; ++k) geoT[(size_t)(l * 64 + m) * 6 + k] = g[k] * inv;
}

// ---------- w[l][i][o][m] = sum_k spec[l][k][i][o][m]*geoT[l][m][k] ----------
__global__ __launch_bounds__(64) void k_w(const float* __restrict__ specw,
                                          const float* __restrict__ geoT,
                                          float* __restrict__ wAll) {
    int l = blockIdx.x >> 12, io = blockIdx.x & 4095;
    int m = threadIdx.x;
    float a = 0.f;
#pragma unroll
    for (int k = 0; k < 6; ++k)
        a += specw[(((size_t)l * 6 + k) * 4096 + io) * 64 + m] * geoT[(size_t)(l * 64 + m) * 6 + k];
    wAll[((size_t)l * 4096 + io) * 64 + m] = a;
}

// ---------- cmc[(b*64+i)*64+m] = INV@z (from Gp partials, INV folded in A) ----------
__global__ __launch_bounds__(256) void k_cmsum(const float* __restrict__ Gp, float* __restrict__ cmc,
                                               int ncols, int colbase, int ns) {
    int bi = blockIdx.x * 4 + (threadIdx.x >> 6);
    int m = threadIdx.x & 63;
    size_t st = (size_t)RA * ncols;
    size_t gi = (size_t)(NN + m) * ncols + colbase + bi;
    cmc[bi * 64 + m] = gpn(Gp, gi, st, ns);
}

// ---------- cgT[b][m][o] = sum_i cmc[b][i][m]*w[i*64+o][m] ----------
__global__ __launch_bounds__(256) void k_cg2(const float* __restrict__ cmc,
                                             const float* __restrict__ wl,
                                             float* __restrict__ cgT) {
    int o = blockIdx.x;
    int b = threadIdx.x >> 6, m = threadIdx.x & 63;
    float acc = 0.f;
    for (int i = 0; i < 64; ++i)
        acc += cmc[(b * 64 + i) * 64 + m] * wl[((size_t)(i * 64 + o)) * 64 + m];
    cgT[(b * 64 + m) * 64 + o] = acc;
}

// ---------- spatial mid -> y in Vt rows 0-255 ----------
__global__ __launch_bounds__(256) void k_spat_mid(const float* __restrict__ Gp,
                           const float* __restrict__ W1, const float* __restrict__ b1,
                           const float* __restrict__ W2, const float* __restrict__ b2,
                           const float* __restrict__ rowsum, bf16_t* __restrict__ Vt,
                           int ncols, int colbase, int ns) {
    __shared__ __align__(16) char buf[64 * XPAD * 4 + 64 * X2PAD * 4];
    float* X  = (float*)buf;
    float* X2 = (float*)(buf + 64 * XPAD * 4);
    bf16_t* ZT = (bf16_t*)buf;
    int t = threadIdx.x, c = t & 63, rq = t >> 6, r0 = rq * 16;
    int bb = blockIdx.x >> 7, n0 = (blockIdx.x & 127) * 64;
    size_t st = (size_t)RA * ncols;
    float rs[16];
#pragma unroll
    for (int q = 0; q < 16; ++q) {
        int m = n0 + r0 + q;
        rs[q] = rowsum[m];
        X[(r0 + q) * XPAD + c] = gpn(Gp, (size_t)m * ncols + colbase + bb * 64 + c, st, ns);
    }
    __syncthreads();
    float ma0[16], ma1[16];
    float b1c0 = b1[c], b1c1 = b1[64 + c];
#pragma unroll
    for (int i = 0; i < 16; ++i) { ma0[i] = rs[i] * b1c0; ma1[i] = rs[i] * b1c1; }
    mm16(X, XPAD, W1, 128, 64, c, r0, ma0);
    mm16(X, XPAD, W1 + 64, 128, 64, c, r0, ma1);
    __syncthreads();
#pragma unroll
    for (int q = 0; q < 16; ++q) {
        X2[(r0 + q) * X2PAD + c] = fmaxf(ma0[q], 0.f);
        X2[(r0 + q) * X2PAD + 64 + c] = fmaxf(ma1[q], 0.f);
    }
    __syncthreads();
    float y[16];
#pragma unroll
    for (int i = 0; i < 16; ++i) y[i] = b2[c];
    mm16(X2, X2PAD, W2, 64, 128, c, r0, y);
#pragma unroll
    for (int q = 0; q < 16; ++q) ZT[c * ZTPAD + r0 + q] = (bf16_t)y[q];
    __syncthreads();
#pragma unroll
    for (int cc = 0; cc < 16; ++cc) {
        int c2 = r0 + cc;
        Vt[(size_t)(bb * 64 + c2) * NN + n0 + c] = ZT[c2 * ZTPAD + c];
    }
}

// ---------- block epilogue (x2 from Gp256, 8 splits) -> z_{l+1} in Vt rows 256+ ----------
__global__ __launch_bounds__(256) void k_blk_post(float* __restrict__ h, const float* __restrict__ Gp,
                           const float* __restrict__ cgT, const float* __restrict__ MP,
                           const float* __restrict__ n1g, const float* __restrict__ n1b,
                           const float* __restrict__ l2g, const float* __restrict__ l2b,
                           const float* __restrict__ prew, const float* __restrict__ preb,
                           const float* __restrict__ postw, const float* __restrict__ postb,
                           const float* __restrict__ zng, const float* __restrict__ znb,
                           bf16_t* __restrict__ Vt, int writeZ) {
    __shared__ __align__(16) char buf[64 * X2PAD * 4 + 64 * XPAD * 4];
    float* MProws = (float*)buf;
    float* X2     = (float*)buf;
    float* X      = (float*)(buf + 64 * X2PAD * 4);
    bf16_t* ZT    = (bf16_t*)(buf + 64 * X2PAD * 4);
    int t = threadIdx.x, c = t & 63, rq = t >> 6, r0 = rq * 16;
    int bb = blockIdx.x >> 7, n0 = (blockIdx.x & 127) * 64;
#pragma unroll
    for (int q = 0; q < 16; ++q)
        MProws[(r0 + q) * XPAD + c] = MP[(size_t)(n0 + r0 + q) * 64 + c];
    __syncthreads();
    float x1[16];
#pragma unroll
    for (int i = 0; i < 16; ++i) x1[i] = 0.f;
    mm16(MProws, XPAD, cgT + (size_t)bb * 4096, 64, 64, c, r0, x1);
    float hv[16];
    float n1gc = n1g[c], n1bc = n1b[c];
#pragma unroll
    for (int q = 0; q < 16; ++q) {
        float s = wsum64(x1[q]), s2 = wsum64(x1[q] * x1[q]);
        float mean = s * (1.f / 64.f), var = s2 * (1.f / 64.f) - mean * mean;
        float x1n = (x1[q] - mean) * rsqrtf(var + 1e-5f) * n1gc + n1bc;
        int n = n0 + r0 + q;
        size_t w = (size_t)bb * NN + n;
        hv[q] = x1n + gp8(Gp, (size_t)n * 256 + bb * 64 + c) + h[w * 64 + c];
    }
    float l2gc = l2g[c], l2bc = l2b[c];
#pragma unroll
    for (int q = 0; q < 16; ++q) {
        float s = wsum64(hv[q]), s2 = wsum64(hv[q] * hv[q]);
        float mean = s * (1.f / 64.f), var = s2 * (1.f / 64.f) - mean * mean;
        X[(r0 + q) * XPAD + c] = (hv[q] - mean) * rsqrtf(var + 1e-5f) * l2gc + l2bc;
    }
    __syncthreads();
    float ma0[16], ma1[16];
    float pb0 = preb[c], pb1 = preb[64 + c];
#pragma unroll
    for (int i = 0; i < 16; ++i) { ma0[i] = pb0; ma1[i] = pb1; }
    mm16(X, XPAD, prew, 128, 64, c, r0, ma0);
    mm16(X, XPAD, prew + 64, 128, 64, c, r0, ma1);
    __syncthreads();
#pragma unroll
    for (int q = 0; q < 16; ++q) {
        X2[(r0 + q) * X2PAD + c] = gelu_f(ma0[q]);
        X2[(r0 + q) * X2PAD + 64 + c] = gelu_f(ma1[q]);
    }
    __syncthreads();
    float o[16];
    float pob = postb[c];
#pragma unroll
    for (int i = 0; i < 16; ++i) o[i] = pob;
    mm16(X2, X2PAD, postw, 64, 128, c, r0, o);
#pragma unroll
    for (int q = 0; q < 16; ++q) {
        hv[q] += o[q];
        h[((size_t)bb * NN + n0 + r0 + q) * 64 + c] = hv[q];
    }
    if (writeZ) {
        float zgc = zng[c], zbc = znb[c];
#pragma unroll
        for (int q = 0; q < 16; ++q) {
            float s = wsum64(hv[q]), s2 = wsum64(hv[q] * hv[q]);
            float mean = s * (1.f / 64.f), var = s2 * (1.f / 64.f) - mean * mean;
            ZT[c * ZTPAD + r0 + q] = (bf16_t)((hv[q] - mean) * rsqrtf(var + 1e-5f) * zgc + zbc);
        }
        __syncthreads();
#pragma unroll
        for (int cc = 0; cc < 16; ++cc) {
            int c2 = r0 + cc;
            Vt[(size_t)(256 + bb * 64 + c2) * NN + n0 + c] = ZT[c2 * ZTPAD + c];
        }
    }
}

// ---------- final head ----------
__global__ __launch_bounds__(256) void k_head(const float* __restrict__ h,
                       const float* __restrict__ g, const float* __restrict__ bb_,
                       const float* __restrict__ fc1w, const float* __restrict__ fc1b,
                       const float* __restrict__ fc2w, const float* __restrict__ fc2b,
                       float* __restrict__ out) {
    __shared__ __align__(16) char buf[64 * XPAD * 4 + 64 * X2PAD * 4];
    float* X  = (float*)buf;
    float* X2 = (float*)(buf + 64 * XPAD * 4);
    int t = threadIdx.x, c = t & 63, rq = t >> 6, r0 = rq * 16;
    int bb = blockIdx.x >> 7, n0 = (blockIdx.x & 127) * 64;
    float gc = g[c], bc = bb_[c];
#pragma unroll
    for (int q = 0; q < 16; ++q) {
        float hv = h[((size_t)bb * NN + n0 + r0 + q) * 64 + c];
        float s = wsum64(hv), s2 = wsum64(hv * hv);
        float mean = s * (1.f / 64.f), var = s2 * (1.f / 64.f) - mean * mean;
        X[(r0 + q) * XPAD + c] = (hv - mean) * rsqrtf(var + 1e-5f) * gc + bc;
    }
    __syncthreads();
    float ma0[16], ma1[16];
    float fb0 = fc1b[c], fb1 = fc1b[64 + c];
#pragma unroll
    for (int i = 0; i < 16; ++i) { ma0[i] = fb0; ma1[i] = fb1; }
    mm16(X, XPAD, fc1w, 128, 64, c, r0, ma0);
    mm16(X, XPAD, fc1w + 64, 128, 64, c, r0, ma1);
    __syncthreads();
#pragma unroll
    for (int q = 0; q < 16; ++q) {
        X2[(r0 + q) * X2PAD + c] = gelu_f(ma0[q]);
        X2[(r0 + q) * X2PAD + 64 + c] = gelu_f(ma1[q]);
    }
    __syncthreads();
    float f2a = fc2w[c], f2b = fc2w[64 + c], f2bias = fc2b[0];
#pragma unroll
    for (int q = 0; q < 16; ++q) {
        float val = X2[(r0 + q) * X2PAD + c] * f2a + X2[(r0 + q) * X2PAD + 64 + c] * f2b;
        val = wsum64(val);
        if (c == 0) out[(size_t)bb * NN + n0 + r0 + q] = val + f2bias;
    }
}

// ---------- bf16 GEMM: 128x128 tile, BK=32, dbuf 32KB, 4 blocks/CU, grid 1040 ----------
// Gp[s][RA][ncols] = A[RA,8192] @ Bt^T ; ncols = ntn*128 ; grid = 65*ntn*ns = 1040
__global__ __launch_bounds__(256, 4) void gemm_bf16(const bf16_t* __restrict__ A,
                                                    const bf16_t* __restrict__ Bt,
                                                    float* __restrict__ Gp,
                                                    int ntn, int ns) {
    __shared__ __align__(16) char smem[2][16384]; // A 8KB + B 8KB per buffer
    // XCD swizzle: grid 1040 = 8 x 130; all 16 (tn,ks) siblings of a tm are adjacent.
    const int cpx = gridDim.x >> 3;
    const int bid = blockIdx.x;
    const int tile = (bid & 7) * cpx + (bid >> 3);
    const int per_tm = ntn * ns;             // 16 for both configs
    const int tm = tile / per_tm;            // 0..64
    const int rem = tile % per_tm;
    const int tn = rem % ntn;
    const int ks = rem / ntn;
    const int nkt = 256 / ns;                // K-steps of 32
    const int kt0 = ks * nkt;
    const int ncols = ntn * 128;

    const int t = threadIdx.x;
    const int lane = t & 63, wid = t >> 6;
    const int wr = wid >> 1, wc = wid & 1;   // 2x2 waves over 128x128
    const int lrow = lane & 15, lk = lane >> 4;

    const bf16_t* Abase = A + (size_t)tm * 128 * NN;
    const bf16_t* Bbase = Bt + (size_t)tn * 128 * NN;

    f32x4 acc[4][4];
#pragma unroll
    for (int i = 0; i < 4; ++i)
#pragma unroll
        for (int j = 0; j < 4; ++j) acc[i][j] = f32x4{0.f, 0.f, 0.f, 0.f};

    auto stage = [&](int bsel, int kt) {
        char* lb = smem[bsel];
        int k0 = kt * 32;
        {
            int ci = t;
            int rw = ci >> 2, ch = ci & 3, sch = ch ^ (rw & 3);
            async16(Abase + (size_t)rw * NN + k0 + sch * 8, lb + ci * 16);
            ci = t + 256;
            rw = ci >> 2; ch = ci & 3; sch = ch ^ (rw & 3);
            async16(Abase + (size_t)rw * NN + k0 + sch * 8, lb + ci * 16);
        }
        {
            int ci = t;
            int rw = ci >> 2, ch = ci & 3, sch = ch ^ (rw & 3);
            async16(Bbase + (size_t)rw * NN + k0 + sch * 8, lb + 8192 + ci * 16);
            ci = t + 256;
            rw = ci >> 2; ch = ci & 3; sch = ch ^ (rw & 3);
            async16(Bbase + (size_t)rw * NN + k0 + sch * 8, lb + 8192 + ci * 16);
        }
    };

    stage(0, kt0);
    __syncthreads();
    for (int it = 0; it < nkt; ++it) {
        int cur = it & 1;
        if (it + 1 < nkt) stage(cur ^ 1, kt0 + it + 1);
        const char* lb = smem[cur];
        bf16x8 av[4], bv[4];
#pragma unroll
        for (int i = 0; i < 4; ++i) {
            int R = wr * 64 + i * 16 + lrow;
            av[i] = *(const bf16x8*)(lb + R * 64 + ((lk ^ (R & 3)) << 4));
        }
#pragma unroll
        for (int j = 0; j < 4; ++j) {
            int Q = wc * 64 + j * 16 + lrow;
            bv[j] = *(const bf16x8*)(lb + 8192 + Q * 64 + ((lk ^ (Q & 3)) << 4));
        }
#pragma unroll
        for (int i = 0; i < 4; ++i)
#pragma unroll
            for (int j = 0; j < 4; ++j)
                acc[i][j] = __builtin_amdgcn_mfma_f32_16x16x32_bf16(av[i], bv[j], acc[i][j], 0, 0, 0);
        __syncthreads();
    }

    float* Cs = Gp + (size_t)ks * RA * ncols;
    const int row0 = tm * 128 + wr * 64;
    const int col0 = tn * 128 + wc * 64;
#pragma unroll
    for (int i = 0; i < 4; ++i)
#pragma unroll
        for (int j = 0; j < 4; ++j)
#pragma unroll
            for (int r = 0; r < 4; ++r)
                Cs[(size_t)(row0 + i * 16 + lk * 4 + r) * ncols + col0 + j * 16 + lrow] = acc[i][j][r];
}

// =====================================================================

extern "C" void kernel_launch(void* const* d_in, const int* in_sizes, int n_in,
                              void* d_out, int out_size, void* d_ws, size_t ws_size,
                              hipStream_t stream) {
    const float* x     = (const float*)d_in[0];
    const float* MP    = (const float*)d_in[1];
    const float* INV   = (const float*)d_in[2];
    const float* mesh  = (const float*)d_in[3];
    const float* adj   = (const float*)d_in[4];
    const float* fc0w  = (const float*)d_in[5];
    const float* fc0b  = (const float*)d_in[6];
    const float* fc01w = (const float*)d_in[7];
    const float* fc01b = (const float*)d_in[8];
    const float* bln1g = (const float*)d_in[9];
    const float* bln1b = (const float*)d_in[10];
    const float* n1g   = (const float*)d_in[11];
    const float* n1b   = (const float*)d_in[12];
    const float* specw = (const float*)d_in[13];
    const float* p1w   = (const float*)d_in[14];
    const float* p1b   = (const float*)d_in[15];
    const float* p2w   = (const float*)d_in[16];
    const float* p2b   = (const float*)d_in[17];
    const float* g1w   = (const float*)d_in[18];
    const float* g1b   = (const float*)d_in[19];
    const float* g2w   = (const float*)d_in[20];
    const float* g2b   = (const float*)d_in[21];
    const float* o1w   = (const float*)d_in[22];
    const float* o1b   = (const float*)d_in[23];
    const float* o2w   = (const float*)d_in[24];
    const float* o2b   = (const float*)d_in[25];
    const float* sg1w  = (const float*)d_in[26];
    const float* sg1b  = (const float*)d_in[27];
    const float* sg2w  = (const float*)d_in[28];
    const float* sg2b  = (const float*)d_in[29];
    const float* bln2g = (const float*)d_in[30];
    const float* bln2b = (const float*)d_in[31];
    const float* prew  = (const float*)d_in[32];
    const float* preb  = (const float*)d_in[33];
    const float* postw = (const float*)d_in[34];
    const float* postb = (const float*)d_in[35];
    const float* ln1g  = (const float*)d_in[36];
    const float* ln1b  = (const float*)d_in[37];
    const float* fc1w  = (const float*)d_in[38];
    const float* fc1b  = (const float*)d_in[39];
    const float* fc2w  = (const float*)d_in[40];
    const float* fc2b  = (const float*)d_in[41];
    float* out = (float*)d_out;

    char* ws = (char*)d_ws;
    bf16_t* adjB    = (bf16_t*)(ws);                       // 136,314,880
    float*  Gp512   = (float*) (ws + 136314880);           // 68,157,440 (4 splits)
    float*  Gp256   = (float*) (ws + 204472320);           // 68,157,440 (8 splits)
    bf16_t* Vt      = (bf16_t*)(ws + 272629760);           // 8,388,608 [512][8192]
    float*  h       = (float*) (ws + 281018368);           // 8,388,608
    float*  rowsum  = (float*) (ws + 289406976);           // 32,768
    float*  partials= (float*) (ws + 289439744);           // 786,432
    float*  geoT    = (float*) (ws + 290226176);           // 6,144
    float*  wAll    = (float*) (ws + 290232320);           // 4,194,304
    float*  cmc     = (float*) (ws + 294426624);           // 65,536
    float*  cgT     = (float*) (ws + 294492160);           // 65,536
    float*  W0b     = (float*) (ws + 294557696);           // 1,280

    bf16_t* VtZ = Vt + (size_t)256 * NN;  // z rows

    // --- static prep ---
    k_adj_convert<<<RA, 256, 0, stream>>>(adj, INV, adjB, rowsum);
    k_fold<<<1, 64, 0, stream>>>(fc0w, fc0b, fc01w, fc01b, W0b);

    // --- encoder GEMM1 (N=256: ntn=2, ns=8, grid 1040) ---
    k_enc_pre<<<512, 256, 0, stream>>>(mesh, p1w, p1b, p2w, p2b, g1w, g1b, Vt);
    gemm_bf16<<<1040, 256, 0, stream>>>(adjB, Vt, Gp256, 2, 8);
    k_enc_mid<<<512, 256, 0, stream>>>(Gp256, g2w, g2b, Vt);
    k_init_h<<<512, 256, 0, stream>>>(x, mesh, W0b, bln1g, bln1b, h, Vt);

    // --- merged GEMM: adj@[t2 | z0] (N=512: ntn=4, ns=4, grid 1040) ---
    gemm_bf16<<<1040, 256, 0, stream>>>(adjB, Vt, Gp512, 4, 4);

    k_geo_part<<<512, 64, 0, stream>>>(Gp512, o1w, o1b, o2w, o2b, INV, partials);
    k_geo_final<<<4, 64, 0, stream>>>(partials, geoT);
    k_w<<<16384, 64, 0, stream>>>(specw, geoT, wAll);

    // --- 4 blocks ---
    for (int l = 0; l < 4; ++l) {
        const float* Gp1 = Gp256; int nc = 256, cb = 0, ns1 = 8;
        if (l == 0) { Gp1 = Gp512; nc = 512; cb = 256; ns1 = 4; }
        else {
            gemm_bf16<<<1040, 256, 0, stream>>>(adjB, VtZ, Gp256, 2, 8);  // adj@z_l + INV@z_l
        }
        k_cmsum<<<64, 256, 0, stream>>>(Gp1, cmc, nc, cb, ns1);
        k_cg2<<<64, 256, 0, stream>>>(cmc, wAll + (size_t)l * 262144, cgT);
        k_spat_mid<<<512, 256, 0, stream>>>(Gp1, sg1w + l * 64 * 128, sg1b + l * 128,
                                            sg2w + l * 128 * 64, sg2b + l * 64, rowsum, Vt,
                                            nc, cb, ns1);
        gemm_bf16<<<1040, 256, 0, stream>>>(adjB, Vt, Gp256, 2, 8);       // x2 = adj@y
        int ln = (l < 3) ? (l + 1) : 3;
        k_blk_post<<<512, 256, 0, stream>>>(h, Gp256, cgT, MP,
                                            n1g + l * 64, n1b + l * 64,
                                            bln2g + l * 64, bln2b + l * 64,
                                            prew + l * 64 * 128, preb + l * 128,
                                            postw + l * 128 * 64, postb + l * 64,
                                            bln1g + ln * 64, bln1b + ln * 64,
                                            Vt, (l < 3) ? 1 : 0);
    }

    k_head<<<512, 256, 0, stream>>>(h, ln1g, ln1b, fc1w, fc1b, fc2w, fc2b, out);
}

// Round 13
// 1281.881 us; speedup vs baseline: 1.1516x; 1.1516x over previous
//
#include <hip/hip_runtime.h>
#include <math.h>

// ---------- types ----------
typedef __bf16 bf16_t;
typedef __bf16 bf16x8 __attribute__((ext_vector_type(8)));
typedef __bf16 bf16x4 __attribute__((ext_vector_type(4)));
typedef float  f32x4  __attribute__((ext_vector_type(4)));

#define NN 8192      // mesh nodes
#define RA 8320      // A rows: 8192 adj + 64 INV + 64 zero pad
#define GP1F 2129920 // RA*256 floats per split-K partial
#define XPAD 68
#define X2PAD 132
#define ZTPAD 66

__device__ __forceinline__ float gelu_f(float x) {
    return 0.5f * x * (1.0f + erff(x * 0.70710678118654752f));
}

__device__ __forceinline__ float wsum64(float v) {
#pragma unroll
    for (int m = 32; m; m >>= 1) v += __shfl_xor(v, m);
    return v;
}

__device__ __forceinline__ float gp4(const float* __restrict__ Gp, size_t gi) {
    return (Gp[gi] + Gp[gi + (size_t)GP1F]) + (Gp[gi + 2 * (size_t)GP1F] + Gp[gi + 3 * (size_t)GP1F]);
}

__device__ __forceinline__ void async16(const void* g, void* l) {
    __builtin_amdgcn_global_load_lds(
        (const __attribute__((address_space(1))) unsigned int*)g,
        (__attribute__((address_space(3))) unsigned int*)l,
        16, 0, 0);
}

// 16-rows-per-thread tile matmul: acc[i] += sum_k X[r0+i][k] * W[k*ws + c]
__device__ __forceinline__ void mm16(const float* __restrict__ X, int xpad,
                                     const float* __restrict__ W, int ws, int K,
                                     int c, int r0, float* acc) {
    for (int k0 = 0; k0 < K; k0 += 4) {
        float w0 = W[(size_t)(k0 + 0) * ws + c];
        float w1 = W[(size_t)(k0 + 1) * ws + c];
        float w2 = W[(size_t)(k0 + 2) * ws + c];
        float w3 = W[(size_t)(k0 + 3) * ws + c];
#pragma unroll
        for (int i = 0; i < 16; ++i) {
            float4 xv = *(const float4*)(X + (size_t)(r0 + i) * xpad + k0);
            acc[i] = fmaf(xv.x, w0, acc[i]);
            acc[i] = fmaf(xv.y, w1, acc[i]);
            acc[i] = fmaf(xv.z, w2, acc[i]);
            acc[i] = fmaf(xv.w, w3, acc[i]);
        }
    }
}

// ---------- adj+INV fp32 -> bf16 + adj row sums (grid 8320) ----------
__global__ __launch_bounds__(256) void k_adj_convert(const float* __restrict__ adj,
                                                     const float* __restrict__ INV,
                                                     bf16_t* __restrict__ adjB,
                                                     float* __restrict__ rowsum) {
    int row = blockIdx.x;
    int t = threadIdx.x;
    bf16_t* br = adjB + (size_t)row * NN;
    if (row >= NN + 64) { // zero pad rows
        bf16x4 zz; zz[0] = zz[1] = zz[2] = zz[3] = (bf16_t)0.f;
#pragma unroll
        for (int v = 0; v < 8; ++v) *(bf16x4*)(br + (v * 256 + t) * 4) = zz;
        return;
    }
    const float* ar = (row < NN) ? adj + (size_t)row * NN : INV + (size_t)(row - NN) * NN;
    float s = 0.f;
#pragma unroll
    for (int v = 0; v < 8; ++v) {
        int i = (v * 256 + t) * 4;
        float4 f = *(const float4*)(ar + i);
        s += f.x + f.y + f.z + f.w;
        bf16x4 o;
        o[0] = (bf16_t)f.x; o[1] = (bf16_t)f.y; o[2] = (bf16_t)f.z; o[3] = (bf16_t)f.w;
        *(bf16x4*)(br + i) = o;
    }
    if (row < NN) {
        s = wsum64(s);
        __shared__ float w4[4];
        if ((t & 63) == 0) w4[t >> 6] = s;
        __syncthreads();
        if (t == 0) rowsum[row] = w4[0] + w4[1] + w4[2] + w4[3];
    }
}

// ---------- fold fc0@fc01 -> W0b[5][64] ----------
__global__ __launch_bounds__(64) void k_fold(const float* __restrict__ fc0w, const float* __restrict__ fc0b,
                                             const float* __restrict__ fc01w, const float* __restrict__ fc01b,
                                             float* __restrict__ W0b) {
    int c = threadIdx.x;
#pragma unroll
    for (int j = 0; j < 4; ++j) {
        float a = 0.f;
        for (int k = 0; k < 64; ++k) a += fc0w[j * 64 + k] * fc01w[k * 64 + c];
        W0b[j * 64 + c] = a;
    }
    float b = fc01b[c];
    for (int k = 0; k < 64; ++k) b += fc0b[k] * fc01w[k * 64 + c];
    W0b[256 + c] = b;
}

// ---------- initial h (folded) + z0 -> Vt ----------
__global__ __launch_bounds__(256) void k_init_h(const float* __restrict__ x, const float* __restrict__ mesh,
                         const float* __restrict__ W0b,
                         const float* __restrict__ zg, const float* __restrict__ zb,
                         float* __restrict__ h, bf16_t* __restrict__ Vt) {
    __shared__ __align__(16) char buf[64 * ZTPAD * 2];
    bf16_t* ZT = (bf16_t*)buf;
    int t = threadIdx.x, c = t & 63, rq = t >> 6, r0 = rq * 16;
    int bb = blockIdx.x >> 7, n0 = (blockIdx.x & 127) * 64;
    float w0c = W0b[c], w1c = W0b[64 + c], w2c = W0b[128 + c], w3c = W0b[192 + c], b0c = W0b[256 + c];
    float gc = zg[c], bc = zb[c];
#pragma unroll
    for (int q = 0; q < 16; ++q) {
        int n = n0 + r0 + q;
        int w = bb * NN + n;
        float xv = x[w];
        float m0 = mesh[n * 3], m1 = mesh[n * 3 + 1], m2 = mesh[n * 3 + 2];
        float hv = b0c + xv * w0c + m0 * w1c + m1 * w2c + m2 * w3c;
        h[(size_t)w * 64 + c] = hv;
        float s = wsum64(hv), s2 = wsum64(hv * hv);
        float mean = s * (1.f / 64.f), var = s2 * (1.f / 64.f) - mean * mean;
        float z = (hv - mean) * rsqrtf(var + 1e-5f) * gc + bc;
        ZT[c * ZTPAD + r0 + q] = (bf16_t)z;
    }
    __syncthreads();
#pragma unroll
    for (int cc = 0; cc < 16; ++cc) {
        int c2 = r0 + cc;
        Vt[(size_t)(bb * 64 + c2) * NN + n0 + c] = ZT[c2 * ZTPAD + c];
    }
}

// ---------- encoder pre ----------
__global__ __launch_bounds__(256) void k_enc_pre(const float* __restrict__ mesh,
                          const float* __restrict__ p1w, const float* __restrict__ p1b,
                          const float* __restrict__ p2w, const float* __restrict__ p2b,
                          const float* __restrict__ g1w, const float* __restrict__ g1b,
                          bf16_t* __restrict__ Vt) {
    __shared__ __align__(16) char buf[2 * 64 * XPAD * 4];
    float* X1 = (float*)buf;
    float* X2 = (float*)(buf + 64 * XPAD * 4);
    bf16_t* ZT = (bf16_t*)buf;
    int t = threadIdx.x, c = t & 63, rq = t >> 6, r0 = rq * 16;
    int ll = blockIdx.x >> 7, n0 = (blockIdx.x & 127) * 64;
    float p1b_c = p1b[ll * 64 + c];
    float p1w0 = p1w[(ll * 3 + 0) * 64 + c], p1w1 = p1w[(ll * 3 + 1) * 64 + c], p1w2 = p1w[(ll * 3 + 2) * 64 + c];
#pragma unroll
    for (int q = 0; q < 16; ++q) {
        int n = n0 + r0 + q;
        float m0 = mesh[n * 3], m1 = mesh[n * 3 + 1], m2 = mesh[n * 3 + 2];
        X1[(r0 + q) * XPAD + c] = gelu_f(p1b_c + m0 * p1w0 + m1 * p1w1 + m2 * p1w2);
    }
    __syncthreads();
    float e2[16];
#pragma unroll
    for (int i = 0; i < 16; ++i) e2[i] = p2b[ll * 64 + c];
    mm16(X1, XPAD, p2w + ll * 4096, 64, 64, c, r0, e2);
    __syncthreads();
#pragma unroll
    for (int q = 0; q < 16; ++q) X2[(r0 + q) * XPAD + c] = e2[q];
    __syncthreads();
    float tt[16];
#pragma unroll
    for (int i = 0; i < 16; ++i) tt[i] = g1b[ll * 64 + c];
    mm16(X2, XPAD, g1w + ll * 4096, 64, 64, c, r0, tt);
#pragma unroll
    for (int q = 0; q < 16; ++q) ZT[c * ZTPAD + r0 + q] = (bf16_t)tt[q];
    __syncthreads();
#pragma unroll
    for (int cc = 0; cc < 16; ++cc) {
        int c2 = r0 + cc;
        Vt[(size_t)(ll * 64 + c2) * NN + n0 + c] = ZT[c2 * ZTPAD + c];
    }
}

// ---------- encoder mid ----------
__global__ __launch_bounds__(256) void k_enc_mid(const float* __restrict__ Gp,
                          const float* __restrict__ g2w, const float* __restrict__ g2b,
                          bf16_t* __restrict__ Vt) {
    __shared__ __align__(16) char buf[64 * XPAD * 4 + 64 * ZTPAD * 2];
    float* X = (float*)buf;
    bf16_t* ZT = (bf16_t*)(buf + 64 * XPAD * 4);
    int t = threadIdx.x, c = t & 63, rq = t >> 6, r0 = rq * 16;
    int ll = blockIdx.x >> 7, n0 = (blockIdx.x & 127) * 64;
#pragma unroll
    for (int q = 0; q < 16; ++q) {
        int n = n0 + r0 + q;
        X[(r0 + q) * XPAD + c] = gelu_f(gp4(Gp, (size_t)n * 256 + ll * 64 + c));
    }
    __syncthreads();
    float t2[16];
#pragma unroll
    for (int i = 0; i < 16; ++i) t2[i] = g2b[ll * 64 + c];
    mm16(X, XPAD, g2w + ll * 4096, 64, 64, c, r0, t2);
#pragma unroll
    for (int q = 0; q < 16; ++q) ZT[c * ZTPAD + r0 + q] = (bf16_t)t2[q];
    __syncthreads();
#pragma unroll
    for (int cc = 0; cc < 16; ++cc) {
        int c2 = r0 + cc;
        Vt[(size_t)(ll * 64 + c2) * NN + n0 + c] = ZT[c2 * ZTPAD + c];
    }
}

// ---------- geo partials ----------
__global__ void k_geo_part(const float* __restrict__ Gp,
                           const float* __restrict__ o1w, const float* __restrict__ o1b,
                           const float* __restrict__ o2w, const float* __restrict__ o2b,
                           const float* __restrict__ INV,
                           float* __restrict__ partials) {
    int l = blockIdx.x >> 7, chunk = blockIdx.x & 127;
    int n0 = chunk * 64;
    int t = threadIdx.x; // 0..63
    __shared__ float e4L[64][65];
    for (int r = 0; r < 64; ++r) {
        size_t gi = (size_t)(n0 + r) * 256 + l * 64 + t;
        e4L[r][t] = gp4(Gp, gi);
    }
    __syncthreads();
    float X[64];
#pragma unroll
    for (int i = 0; i < 64; ++i) X[i] = e4L[t][i];
    float e5[6] = {0, 0, 0, 0, 0, 0};
    const float* o1wl = o1w + (size_t)l * 64 * 128;
    const float* o2wl = o2w + (size_t)l * 128 * 6;
    for (int j = 0; j < 128; ++j) {
        float a = o1b[l * 128 + j];
#pragma unroll
        for (int i = 0; i < 64; ++i) a += X[i] * o1wl[i * 128 + j];
#pragma unroll
        for (int k = 0; k < 6; ++k) e5[k] += a * o2wl[j * 6 + k];
    }
#pragma unroll
    for (int k = 0; k < 6; ++k) e5[k] += o2b[l * 6 + k];
    __shared__ float e5L[64][8];
#pragma unroll
    for (int k = 0; k < 6; ++k) e5L[t][k] = e5[k];
    __syncthreads();
    float p[6] = {0, 0, 0, 0, 0, 0};
    const float* ivr = INV + (size_t)t * NN + n0;
    for (int r = 0; r < 64; ++r) {
        float iv = ivr[r];
#pragma unroll
        for (int k = 0; k < 6; ++k) p[k] += iv * e5L[r][k];
    }
#pragma unroll
    for (int k = 0; k < 6; ++k) partials[(size_t)(((l * 128 + chunk) * 64) + t) * 6 + k] = p[k];
}

// ---------- geo reduce + softmax ----------
__global__ void k_geo_final(const float* __restrict__ partials, float* __restrict__ geoT) {
    int l = blockIdx.x, m = threadIdx.x;
    float g[6] = {0, 0, 0, 0, 0, 0};
    for (int ch = 0; ch < 128; ++ch) {
#pragma unroll
        for (int k = 0; k < 6; ++k) g[k] += partials[(size_t)(((l * 128 + ch) * 64) + m) * 6 + k];
    }
    float mx = g[0];
#pragma unroll
    for (int k = 1; k < 6; ++k) mx = fmaxf(mx, g[k]);
    float s = 0.f;
#pragma unroll
    for (int k = 0; k < 6; ++k) { g[k] = expf(g[k] - mx); s += g[k]; }
    float inv = 1.f / s;
#pragma unroll
    for (int k = 0; k < 6; ++k) geoT[(size_t)(l * 64 + m) * 6 + k] = g[k] * inv;
}

// ---------- w[l][i][o][m] = sum_k spec[l][k][i][o][m]*geoT[l][m][k] ----------
__global__ __launch_bounds__(64) void k_w(const float* __restrict__ specw,
                                          const float* __restrict__ geoT,
                                          float* __restrict__ wAll) {
    int l = blockIdx.x >> 12, io = blockIdx.x & 4095;
    int m = threadIdx.x;
    float a = 0.f;
#pragma unroll
    for (int k = 0; k < 6; ++k)
        a += specw[(((size_t)l * 6 + k) * 4096 + io) * 64 + m] * geoT[(size_t)(l * 64 + m) * 6 + k];
    wAll[((size_t)l * 4096 + io) * 64 + m] = a;
}

// ---------- cmc[(b*64+i)*64+m] = sum_s Gp[s][8192+m][b*64+i] ----------
__global__ __launch_bounds__(256) void k_cmsum(const float* __restrict__ Gp, float* __restrict__ cmc) {
    int bi = blockIdx.x * 4 + (threadIdx.x >> 6);
    int m = threadIdx.x & 63;
    size_t gi = (size_t)(NN + m) * 256 + bi;
    cmc[bi * 64 + m] = gp4(Gp, gi);
}

// ---------- cgT[b][m][o] = sum_i cmc[b][i][m]*w[i*64+o][m] ----------
__global__ __launch_bounds__(256) void k_cg2(const float* __restrict__ cmc,
                                             const float* __restrict__ wl,
                                             float* __restrict__ cgT) {
    int o = blockIdx.x;
    int b = threadIdx.x >> 6, m = threadIdx.x & 63;
    float acc = 0.f;
    for (int i = 0; i < 64; ++i)
        acc += cmc[(b * 64 + i) * 64 + m] * wl[((size_t)(i * 64 + o)) * 64 + m];
    cgT[(b * 64 + m) * 64 + o] = acc;
}

// ---------- spatial mid ----------
__global__ __launch_bounds__(256) void k_spat_mid(const float* __restrict__ Gp,
                           const float* __restrict__ W1, const float* __restrict__ b1,
                           const float* __restrict__ W2, const float* __restrict__ b2,
                           const float* __restrict__ rowsum, bf16_t* __restrict__ Vt) {
    __shared__ __align__(16) char buf[64 * XPAD * 4 + 64 * X2PAD * 4];
    float* X  = (float*)buf;
    float* X2 = (float*)(buf + 64 * XPAD * 4);
    bf16_t* ZT = (bf16_t*)buf;
    int t = threadIdx.x, c = t & 63, rq = t >> 6, r0 = rq * 16;
    int bb = blockIdx.x >> 7, n0 = (blockIdx.x & 127) * 64;
    float rs[16];
#pragma unroll
    for (int q = 0; q < 16; ++q) {
        int m = n0 + r0 + q;
        rs[q] = rowsum[m];
        X[(r0 + q) * XPAD + c] = gp4(Gp, (size_t)m * 256 + bb * 64 + c);
    }
    __syncthreads();
    float ma0[16], ma1[16];
    float b1c0 = b1[c], b1c1 = b1[64 + c];
#pragma unroll
    for (int i = 0; i < 16; ++i) { ma0[i] = rs[i] * b1c0; ma1[i] = rs[i] * b1c1; }
    mm16(X, XPAD, W1, 128, 64, c, r0, ma0);
    mm16(X, XPAD, W1 + 64, 128, 64, c, r0, ma1);
    __syncthreads();
#pragma unroll
    for (int q = 0; q < 16; ++q) {
        X2[(r0 + q) * X2PAD + c] = fmaxf(ma0[q], 0.f);
        X2[(r0 + q) * X2PAD + 64 + c] = fmaxf(ma1[q], 0.f);
    }
    __syncthreads();
    float y[16];
#pragma unroll
    for (int i = 0; i < 16; ++i) y[i] = b2[c];
    mm16(X2, X2PAD, W2, 64, 128, c, r0, y);
#pragma unroll
    for (int q = 0; q < 16; ++q) ZT[c * ZTPAD + r0 + q] = (bf16_t)y[q];
    __syncthreads();
#pragma unroll
    for (int cc = 0; cc < 16; ++cc) {
        int c2 = r0 + cc;
        Vt[(size_t)(bb * 64 + c2) * NN + n0 + c] = ZT[c2 * ZTPAD + c];
    }
}

// ---------- block epilogue (+ fused z_{l+1}) ----------
__global__ __launch_bounds__(256) void k_blk_post(float* __restrict__ h, const float* __restrict__ Gp,
                           const float* __restrict__ cgT, const float* __restrict__ MP,
                           const float* __restrict__ n1g, const float* __restrict__ n1b,
                           const float* __restrict__ l2g, const float* __restrict__ l2b,
                           const float* __restrict__ prew, const float* __restrict__ preb,
                           const float* __restrict__ postw, const float* __restrict__ postb,
                           const float* __restrict__ zng, const float* __restrict__ znb,
                           bf16_t* __restrict__ Vt, int writeZ) {
    __shared__ __align__(16) char buf[64 * X2PAD * 4 + 64 * XPAD * 4];
    float* MProws = (float*)buf;
    float* X2     = (float*)buf;
    float* X      = (float*)(buf + 64 * X2PAD * 4);
    bf16_t* ZT    = (bf16_t*)(buf + 64 * X2PAD * 4);
    int t = threadIdx.x, c = t & 63, rq = t >> 6, r0 = rq * 16;
    int bb = blockIdx.x >> 7, n0 = (blockIdx.x & 127) * 64;
#pragma unroll
    for (int q = 0; q < 16; ++q)
        MProws[(r0 + q) * XPAD + c] = MP[(size_t)(n0 + r0 + q) * 64 + c];
    __syncthreads();
    float x1[16];
#pragma unroll
    for (int i = 0; i < 16; ++i) x1[i] = 0.f;
    mm16(MProws, XPAD, cgT + (size_t)bb * 4096, 64, 64, c, r0, x1);
    float hv[16];
    float n1gc = n1g[c], n1bc = n1b[c];
#pragma unroll
    for (int q = 0; q < 16; ++q) {
        float s = wsum64(x1[q]), s2 = wsum64(x1[q] * x1[q]);
        float mean = s * (1.f / 64.f), var = s2 * (1.f / 64.f) - mean * mean;
        float x1n = (x1[q] - mean) * rsqrtf(var + 1e-5f) * n1gc + n1bc;
        int n = n0 + r0 + q;
        size_t w = (size_t)bb * NN + n;
        hv[q] = x1n + gp4(Gp, (size_t)n * 256 + bb * 64 + c) + h[w * 64 + c];
    }
    float l2gc = l2g[c], l2bc = l2b[c];
#pragma unroll
    for (int q = 0; q < 16; ++q) {
        float s = wsum64(hv[q]), s2 = wsum64(hv[q] * hv[q]);
        float mean = s * (1.f / 64.f), var = s2 * (1.f / 64.f) - mean * mean;
        X[(r0 + q) * XPAD + c] = (hv[q] - mean) * rsqrtf(var + 1e-5f) * l2gc + l2bc;
    }
    __syncthreads();
    float ma0[16], ma1[16];
    float pb0 = preb[c], pb1 = preb[64 + c];
#pragma unroll
    for (int i = 0; i < 16; ++i) { ma0[i] = pb0; ma1[i] = pb1; }
    mm16(X, XPAD, prew, 128, 64, c, r0, ma0);
    mm16(X, XPAD, prew + 64, 128, 64, c, r0, ma1);
    __syncthreads();
#pragma unroll
    for (int q = 0; q < 16; ++q) {
        X2[(r0 + q) * X2PAD + c] = gelu_f(ma0[q]);
        X2[(r0 + q) * X2PAD + 64 + c] = gelu_f(ma1[q]);
    }
    __syncthreads();
    float o[16];
    float pob = postb[c];
#pragma unroll
    for (int i = 0; i < 16; ++i) o[i] = pob;
    mm16(X2, X2PAD, postw, 64, 128, c, r0, o);
#pragma unroll
    for (int q = 0; q < 16; ++q) {
        hv[q] += o[q];
        h[((size_t)bb * NN + n0 + r0 + q) * 64 + c] = hv[q];
    }
    if (writeZ) {
        float zgc = zng[c], zbc = znb[c];
#pragma unroll
        for (int q = 0; q < 16; ++q) {
            float s = wsum64(hv[q]), s2 = wsum64(hv[q] * hv[q]);
            float mean = s * (1.f / 64.f), var = s2 * (1.f / 64.f) - mean * mean;
            ZT[c * ZTPAD + r0 + q] = (bf16_t)((hv[q] - mean) * rsqrtf(var + 1e-5f) * zgc + zbc);
        }
        __syncthreads();
#pragma unroll
        for (int cc = 0; cc < 16; ++cc) {
            int c2 = r0 + cc;
            Vt[(size_t)(bb * 64 + c2) * NN + n0 + c] = ZT[c2 * ZTPAD + c];
        }
    }
}

// ---------- final head ----------
__global__ __launch_bounds__(256) void k_head(const float* __restrict__ h,
                       const float* __restrict__ g, const float* __restrict__ bb_,
                       const float* __restrict__ fc1w, const float* __restrict__ fc1b,
                       const float* __restrict__ fc2w, const float* __restrict__ fc2b,
                       float* __restrict__ out) {
    __shared__ __align__(16) char buf[64 * XPAD * 4 + 64 * X2PAD * 4];
    float* X  = (float*)buf;
    float* X2 = (float*)(buf + 64 * XPAD * 4);
    int t = threadIdx.x, c = t & 63, rq = t >> 6, r0 = rq * 16;
    int bb = blockIdx.x >> 7, n0 = (blockIdx.x & 127) * 64;
    float gc = g[c], bc = bb_[c];
#pragma unroll
    for (int q = 0; q < 16; ++q) {
        float hv = h[((size_t)bb * NN + n0 + r0 + q) * 64 + c];
        float s = wsum64(hv), s2 = wsum64(hv * hv);
        float mean = s * (1.f / 64.f), var = s2 * (1.f / 64.f) - mean * mean;
        X[(r0 + q) * XPAD + c] = (hv - mean) * rsqrtf(var + 1e-5f) * gc + bc;
    }
    __syncthreads();
    float ma0[16], ma1[16];
    float fb0 = fc1b[c], fb1 = fc1b[64 + c];
#pragma unroll
    for (int i = 0; i < 16; ++i) { ma0[i] = fb0; ma1[i] = fb1; }
    mm16(X, XPAD, fc1w, 128, 64, c, r0, ma0);
    mm16(X, XPAD, fc1w + 64, 128, 64, c, r0, ma1);
    __syncthreads();
#pragma unroll
    for (int q = 0; q < 16; ++q) {
        X2[(r0 + q) * X2PAD + c] = gelu_f(ma0[q]);
        X2[(r0 + q) * X2PAD + 64 + c] = gelu_f(ma1[q]);
    }
    __syncthreads();
    float f2a = fc2w[c], f2b = fc2w[64 + c], f2bias = fc2b[0];
#pragma unroll
    for (int q = 0; q < 16; ++q) {
        float val = X2[(r0 + q) * X2PAD + c] * f2a + X2[(r0 + q) * X2PAD + 64 + c] * f2b;
        val = wsum64(val);
        if (c == 0) out[(size_t)bb * NN + n0 + r0 + q] = val + f2bias;
    }
}

// ---------- bf16 GEMM split-K=4, XCD-swizzled: Gp[s][8320][256] = A@Bt^T ----------
__global__ __launch_bounds__(256) void gemm_bf16(const bf16_t* __restrict__ A,
                                                 const bf16_t* __restrict__ Bt,
                                                 float* __restrict__ Gp) {
    __shared__ __align__(16) char smem[2][24576]; // A 16KB + B 8KB per buffer
    // XCD-aware swizzle: grid 1040 = 8 XCDs x 130; siblings (same tm, tn 0..3)
    // are adjacent tiles -> same XCD chunk -> A rows hit that XCD's L2 once.
    const int bid = blockIdx.x;
    const int tile = (bid & 7) * 130 + (bid >> 3);   // 0..1039
    const int ks = tile / 260;                       // 0..3
    const int r2 = tile % 260;
    const int tn = r2 & 3;
    const int tm = r2 >> 2;                          // 0..64
    const int kt0 = ks * 32;
    const int nkt = 32;

    const int t = threadIdx.x;
    const int lane = t & 63, wid = t >> 6;
    const int wr = wid >> 1, wc = wid & 1;
    const int lrow = lane & 15, lk = lane >> 4;

    const bf16_t* Abase = A + (size_t)tm * 128 * NN;
    const bf16_t* Bbase = Bt + (size_t)tn * 64 * NN;

    f32x4 acc[4][2];
#pragma unroll
    for (int i = 0; i < 4; ++i) {
        acc[i][0] = f32x4{0.f, 0.f, 0.f, 0.f};
        acc[i][1] = f32x4{0.f, 0.f, 0.f, 0.f};
    }

    auto stage = [&](int bsel, int kt) {
        char* lb = smem[bsel];
        int k0 = kt * 64;
#pragma unroll
        for (int r = 0; r < 4; ++r) {
            int ci = t + r * 256;
            int rw = ci >> 3, ch = ci & 7;
            int sch = ch ^ (rw & 7);
            async16(Abase + (size_t)rw * NN + k0 + sch * 8, lb + ci * 16);
        }
#pragma unroll
        for (int r = 0; r < 2; ++r) {
            int ci = t + r * 256;
            int rw = ci >> 3, ch = ci & 7;
            int sch = ch ^ (rw & 7);
            async16(Bbase + (size_t)rw * NN + k0 + sch * 8, lb + 16384 + ci * 16);
        }
    };

    stage(0, kt0);
    __syncthreads();
    for (int it = 0; it < nkt; ++it) {
        int cur = it & 1;
        if (it + 1 < nkt) stage(cur ^ 1, kt0 + it + 1);
        const char* lb = smem[cur];
#pragma unroll
        for (int kk = 0; kk < 2; ++kk) {
            bf16x8 av[4], bv[2];
#pragma unroll
            for (int i = 0; i < 4; ++i) {
                int R = wr * 64 + i * 16 + lrow;
                av[i] = *(const bf16x8*)(lb + R * 128 + (((kk * 4 + lk) ^ (R & 7)) << 4));
            }
#pragma unroll
            for (int j = 0; j < 2; ++j) {
                int Q = wc * 32 + j * 16 + lrow;
                bv[j] = *(const bf16x8*)(lb + 16384 + Q * 128 + (((kk * 4 + lk) ^ (Q & 7)) << 4));
            }
#pragma unroll
            for (int i = 0; i < 4; ++i)
#pragma unroll
                for (int j = 0; j < 2; ++j)
                    acc[i][j] = __builtin_amdgcn_mfma_f32_16x16x32_bf16(av[i], bv[j], acc[i][j], 0, 0, 0);
        }
        __syncthreads();
    }

    float* Cs = Gp + (size_t)ks * GP1F;
    int row0 = tm * 128 + wr * 64;
    int col0 = tn * 64 + wc * 32;
#pragma unroll
    for (int i = 0; i < 4; ++i)
#pragma unroll
        for (int j = 0; j < 2; ++j)
#pragma unroll
            for (int r = 0; r < 4; ++r)
                Cs[(size_t)(row0 + i * 16 + lk * 4 + r) * 256 + col0 + j * 16 + lrow] = acc[i][j][r];
}

// =====================================================================

extern "C" void kernel_launch(void* const* d_in, const int* in_sizes, int n_in,
                              void* d_out, int out_size, void* d_ws, size_t ws_size,
                              hipStream_t stream) {
    const float* x     = (const float*)d_in[0];
    const float* MP    = (const float*)d_in[1];
    const float* INV   = (const float*)d_in[2];
    const float* mesh  = (const float*)d_in[3];
    const float* adj   = (const float*)d_in[4];
    const float* fc0w  = (const float*)d_in[5];
    const float* fc0b  = (const float*)d_in[6];
    const float* fc01w = (const float*)d_in[7];
    const float* fc01b = (const float*)d_in[8];
    const float* bln1g = (const float*)d_in[9];
    const float* bln1b = (const float*)d_in[10];
    const float* n1g   = (const float*)d_in[11];
    const float* n1b   = (const float*)d_in[12];
    const float* specw = (const float*)d_in[13];
    const float* p1w   = (const float*)d_in[14];
    const float* p1b   = (const float*)d_in[15];
    const float* p2w   = (const float*)d_in[16];
    const float* p2b   = (const float*)d_in[17];
    const float* g1w   = (const float*)d_in[18];
    const float* g1b   = (const float*)d_in[19];
    const float* g2w   = (const float*)d_in[20];
    const float* g2b   = (const float*)d_in[21];
    const float* o1w   = (const float*)d_in[22];
    const float* o1b   = (const float*)d_in[23];
    const float* o2w   = (const float*)d_in[24];
    const float* o2b   = (const float*)d_in[25];
    const float* sg1w  = (const float*)d_in[26];
    const float* sg1b  = (const float*)d_in[27];
    const float* sg2w  = (const float*)d_in[28];
    const float* sg2b  = (const float*)d_in[29];
    const float* bln2g = (const float*)d_in[30];
    const float* bln2b = (const float*)d_in[31];
    const float* prew  = (const float*)d_in[32];
    const float* preb  = (const float*)d_in[33];
    const float* postw = (const float*)d_in[34];
    const float* postb = (const float*)d_in[35];
    const float* ln1g  = (const float*)d_in[36];
    const float* ln1b  = (const float*)d_in[37];
    const float* fc1w  = (const float*)d_in[38];
    const float* fc1b  = (const float*)d_in[39];
    const float* fc2w  = (const float*)d_in[40];
    const float* fc2b  = (const float*)d_in[41];
    float* out = (float*)d_out;

    char* ws = (char*)d_ws;
    bf16_t* adjB    = (bf16_t*)(ws);                       // 136,314,880
    float*  Gp      = (float*) (ws + 136314880);           // 34,078,720 (4 splits)
    bf16_t* Vt      = (bf16_t*)(ws + 170393600);           // 4,194,304
    float*  h       = (float*) (ws + 174587904);           // 8,388,608
    float*  rowsum  = (float*) (ws + 182976512);           // 32,768
    float*  partials= (float*) (ws + 183009280);           // 786,432
    float*  geoT    = (float*) (ws + 183795712);           // 6,144
    float*  wAll    = (float*) (ws + 183801856);           // 4,194,304
    float*  cmc     = (float*) (ws + 187996160);           // 65,536
    float*  cgT     = (float*) (ws + 188061696);           // 65,536
    float*  W0b     = (float*) (ws + 188127232);           // 1,280

    // --- static prep ---
    k_adj_convert<<<RA, 256, 0, stream>>>(adj, INV, adjB, rowsum);
    k_fold<<<1, 64, 0, stream>>>(fc0w, fc0b, fc01w, fc01b, W0b);

    // --- encoder for all 4 blocks ---
    k_enc_pre<<<512, 256, 0, stream>>>(mesh, p1w, p1b, p2w, p2b, g1w, g1b, Vt);
    gemm_bf16<<<1040, 256, 0, stream>>>(adjB, Vt, Gp);
    k_enc_mid<<<512, 256, 0, stream>>>(Gp, g2w, g2b, Vt);
    gemm_bf16<<<1040, 256, 0, stream>>>(adjB, Vt, Gp);
    k_geo_part<<<512, 64, 0, stream>>>(Gp, o1w, o1b, o2w, o2b, INV, partials);
    k_geo_final<<<4, 64, 0, stream>>>(partials, geoT);
    k_w<<<16384, 64, 0, stream>>>(specw, geoT, wAll);

    // --- h init (+z0) ---
    k_init_h<<<512, 256, 0, stream>>>(x, mesh, W0b, bln1g, bln1b, h, Vt);

    // --- 4 blocks ---
    for (int l = 0; l < 4; ++l) {
        gemm_bf16<<<1040, 256, 0, stream>>>(adjB, Vt, Gp);   // adj@z + INV@z
        k_cmsum<<<64, 256, 0, stream>>>(Gp, cmc);
        k_cg2<<<64, 256, 0, stream>>>(cmc, wAll + (size_t)l * 262144, cgT);
        k_spat_mid<<<512, 256, 0, stream>>>(Gp, sg1w + l * 64 * 128, sg1b + l * 128,
                                            sg2w + l * 128 * 64, sg2b + l * 64, rowsum, Vt);
        gemm_bf16<<<1040, 256, 0, stream>>>(adjB, Vt, Gp);   // x2 = adj@y
        int ln = (l < 3) ? (l + 1) : 3;
        k_blk_post<<<512, 256, 0, stream>>>(h, Gp, cgT, MP,
                                            n1g + l * 64, n1b + l * 64,
                                            bln2g + l * 64, bln2b + l * 64,
                                            prew + l * 64 * 128, preb + l * 128,
                                            postw + l * 128 * 64, postb + l * 64,
                                            bln1g + ln * 64, bln1b + ln * 64,
                                            Vt, (l < 3) ? 1 : 0);
    }

    k_head<<<512, 256, 0, stream>>>(h, ln1g, ln1b, fc1w, fc1b, fc2w, fc2b, out);
}